// Round 1
// baseline (536.582 us; speedup 1.0000x reference)
//
#include <hip/hip_runtime.h>
#include <hip/hip_bf16.h>

typedef __hip_bfloat16 bf16;
typedef __attribute__((ext_vector_type(8))) short short8;   // 8 bf16 (4 VGPR) MFMA frag
typedef __attribute__((ext_vector_type(4))) float f32x4;    // MFMA accumulator

#define N_ 32768
#define D_ 256
#define S_ 256
#define B_ 128
#define E_ 524288

static __device__ __forceinline__ f32x4 mfma16(short8 a, short8 b, f32x4 c) {
  return __builtin_amdgcn_mfma_f32_16x16x32_bf16(a, b, c, 0, 0, 0);
}
static __device__ __forceinline__ f32x4 fzero4() {
  f32x4 z; z[0] = 0.f; z[1] = 0.f; z[2] = 0.f; z[3] = 0.f; return z;
}
static __device__ __forceinline__ float tof(float x) { return x; }
static __device__ __forceinline__ float tof(bf16 x) { return __bfloat162float(x); }

// ---------------------------------------------------------------------------
// Generic bf16 MFMA GEMM:  C = epilogue(A @ Bt^T [+ bias] [+ resid])
// A: [M][K] bf16 row-major.  Bt: [Nc][K] bf16 row-major (i.e. B transposed).
// Tile 128x128, BK=32, 4 waves (2x2), each wave 64x64 (4x4 frags of 16x16).
// Flags: 1=relu, 2=bias, 4=resid(f32), 8=write f32, 16=write bf16.
// ---------------------------------------------------------------------------
#define BM 128
#define BNT 128
#define BK 32
#define LDK 40   // padded LDS stride (80B, 16B-aligned, conflict-free b128)

template<int F>
__global__ __launch_bounds__(256)
void gemm_bt(const bf16* __restrict__ A, const bf16* __restrict__ Bt,
             const float* __restrict__ bias, const float* __restrict__ resid,
             float* __restrict__ Cf, bf16* __restrict__ Cb,
             int M, int Nc, int K, long bsA, long bsB, long bsC)
{
  __shared__ __align__(16) bf16 lA[BM * LDK];
  __shared__ __align__(16) bf16 lB[BNT * LDK];
  const int z = blockIdx.z;
  const bf16* Ab = A + (long)z * bsA;
  const bf16* Bb = Bt + (long)z * bsB;
  const int m0 = blockIdx.x * BM, n0 = blockIdx.y * BNT;
  const int tid = threadIdx.x;
  const int lane = tid & 63;
  const int w = tid >> 6, wr = w >> 1, wc = w & 1;
  const int g = lane >> 4, r = lane & 15, ko = g * 8;

  f32x4 acc[4][4];
  for (int i = 0; i < 4; i++) for (int j = 0; j < 4; j++) acc[i][j] = fzero4();

  const int ar0 = tid >> 2,          ak0 = (tid & 3) * 8;
  const int ar1 = (tid + 256) >> 2,  ak1 = ((tid + 256) & 3) * 8;

  for (int k0 = 0; k0 < K; k0 += BK) {
    short8 va0 = *(const short8*)(Ab + (long)(m0 + ar0) * K + k0 + ak0);
    short8 va1 = *(const short8*)(Ab + (long)(m0 + ar1) * K + k0 + ak1);
    short8 vb0 = *(const short8*)(Bb + (long)(n0 + ar0) * K + k0 + ak0);
    short8 vb1 = *(const short8*)(Bb + (long)(n0 + ar1) * K + k0 + ak1);
    __syncthreads();
    *(short8*)&lA[ar0 * LDK + ak0] = va0;
    *(short8*)&lA[ar1 * LDK + ak1] = va1;
    *(short8*)&lB[ar0 * LDK + ak0] = vb0;
    *(short8*)&lB[ar1 * LDK + ak1] = vb1;
    __syncthreads();
    short8 af[4], bfv[4];
    for (int mi = 0; mi < 4; mi++)
      af[mi] = *(const short8*)&lA[(wr * 64 + mi * 16 + r) * LDK + ko];
    for (int ni = 0; ni < 4; ni++)
      bfv[ni] = *(const short8*)&lB[(wc * 64 + ni * 16 + r) * LDK + ko];
    for (int mi = 0; mi < 4; mi++)
      for (int ni = 0; ni < 4; ni++)
        acc[mi][ni] = mfma16(af[mi], bfv[ni], acc[mi][ni]);
  }

  for (int mi = 0; mi < 4; mi++) for (int ni = 0; ni < 4; ni++) {
    const int row = m0 + wr * 64 + mi * 16 + g * 4;   // C/D: row=(lane>>4)*4+reg
    const int col = n0 + wc * 64 + ni * 16 + r;       //      col=lane&15
    float bv = (F & 2) ? bias[col] : 0.0f;
    for (int j = 0; j < 4; j++) {
      long idx = (long)(row + j) * Nc + col;
      float v = acc[mi][ni][j] + bv;
      if (F & 4) v += resid[idx];
      if (F & 1) v = fmaxf(v, 0.0f);
      if (F & 8)  Cf[(long)z * bsC + idx] = v;
      if (F & 16) Cb[(long)z * bsC + idx] = __float2bfloat16(v);
    }
  }
}

// ---------------------------------------------------------------------------
// Fused attention: one block per (qtile=64 rows, head, batch). 4 waves; each
// wave owns 16 q-rows. QK^T via MFMA, in-register softmax (shfl over 16-lane
// group), P->LDS (bf16), PV via MFMA, normalize in epilogue.
// qh,kh: [N][D] bf16.  vt: [B][H][32][256] bf16 (V transposed). ob: [N][D] bf16.
// ---------------------------------------------------------------------------
__global__ __launch_bounds__(256)
void attn_k(const bf16* __restrict__ qh, const bf16* __restrict__ kh,
            const bf16* __restrict__ vt, bf16* __restrict__ ob)
{
  const int qt = blockIdx.x, h = blockIdx.y, b = blockIdx.z;
  const int tid = threadIdx.x, lane = tid & 63, w = tid >> 6;
  const int g = lane >> 4, r = lane & 15, ko = g * 8;
  __shared__ __align__(16) bf16 lQ[64 * 40];
  __shared__ __align__(16) bf16 lK[256 * 40];
  __shared__ __align__(16) bf16 lV[32 * 264];
  __shared__ __align__(16) bf16 lP[4][16 * 264];

  { int row = tid >> 2, c = (tid & 3) * 8;
    *(short8*)&lQ[row * 40 + c] =
      *(const short8*)(qh + (long)(b * 256 + qt * 64 + row) * 256 + h * 32 + c); }
  for (int i = 0; i < 4; i++) {
    int s = tid + i * 256; int row = s >> 2, c = (s & 3) * 8;
    *(short8*)&lK[row * 40 + c] =
      *(const short8*)(kh + (long)(b * 256 + row) * 256 + h * 32 + c);
  }
  const bf16* vbp = vt + (long)(b * 8 + h) * 8192;
  for (int i = 0; i < 4; i++) {
    int s = tid + i * 256; int row = s >> 5, c = (s & 31) * 8;
    *(short8*)&lV[row * 264 + c] = *(const short8*)(vbp + row * 256 + c);
  }
  __syncthreads();

  short8 aq = *(const short8*)&lQ[(w * 16 + r) * 40 + ko];
  f32x4 sc[16];
  for (int nc = 0; nc < 16; nc++) {
    short8 bk = *(const short8*)&lK[(nc * 16 + r) * 40 + ko];
    sc[nc] = mfma16(aq, bk, fzero4());
  }
  const float scale = 0.17677669529663687f;  // 1/sqrt(32)
  float rsum[4];
  for (int j = 0; j < 4; j++) {
    float mx = -3.4e38f;
    for (int nc = 0; nc < 16; nc++) mx = fmaxf(mx, sc[nc][j]);
    mx = fmaxf(mx, __shfl_xor(mx, 1));
    mx = fmaxf(mx, __shfl_xor(mx, 2));
    mx = fmaxf(mx, __shfl_xor(mx, 4));
    mx = fmaxf(mx, __shfl_xor(mx, 8));
    float sum = 0.f;
    for (int nc = 0; nc < 16; nc++) {
      float p = __expf((sc[nc][j] - mx) * scale);
      sc[nc][j] = p; sum += p;
    }
    sum += __shfl_xor(sum, 1); sum += __shfl_xor(sum, 2);
    sum += __shfl_xor(sum, 4); sum += __shfl_xor(sum, 8);
    rsum[j] = sum;
    for (int nc = 0; nc < 16; nc++)
      lP[w][(g * 4 + j) * 264 + nc * 16 + r] = __float2bfloat16(sc[nc][j]);
  }
  __syncthreads();
  f32x4 oa[2]; oa[0] = fzero4(); oa[1] = fzero4();
  for (int kc = 0; kc < 8; kc++) {
    short8 ap = *(const short8*)&lP[w][r * 264 + kc * 32 + ko];
    for (int n = 0; n < 2; n++) {
      short8 bv = *(const short8*)&lV[(n * 16 + r) * 264 + kc * 32 + ko];
      oa[n] = mfma16(ap, bv, oa[n]);
    }
  }
  for (int n = 0; n < 2; n++) for (int j = 0; j < 4; j++) {
    float v = oa[n][j] / rsum[j];
    ob[(long)(b * 256 + qt * 64 + w * 16 + g * 4 + j) * 256 + h * 32 + n * 16 + r] =
      __float2bfloat16(v);
  }
}

// ---------------------------------------------------------------------------
// Tiled transpose + cast to bf16. in: [rows][in_rs] (TIN), per-z offset
// (z/zdiv)*zhi + (z%zdiv)*zlo. out[c][r] layout with row-stride out_rs,
// per-z offset z*out_zs. Block (32,8), grid (cols/32, rows/32, Z).
// ---------------------------------------------------------------------------
template<typename TIN>
__global__ __launch_bounds__(256)
void transpose_cast_k(const TIN* __restrict__ in, bf16* __restrict__ out,
                      int in_rs, int out_rs, long zhi, long zlo, int zdiv, long out_zs)
{
  __shared__ float tile[32][33];
  const int z = blockIdx.z;
  const long ioff = (long)(z / zdiv) * zhi + (long)(z % zdiv) * zlo;
  const long ooff = (long)z * out_zs;
  const int tx = threadIdx.x, ty = threadIdx.y;
  const int c = blockIdx.x * 32 + tx;
  const int rb = blockIdx.y * 32;
  for (int i = 0; i < 4; i++)
    tile[ty + i * 8][tx] = tof(in[ioff + (long)(rb + ty + i * 8) * in_rs + c]);
  __syncthreads();
  const int oc = rb + tx;
  const int orb = blockIdx.x * 32;
  for (int i = 0; i < 4; i++)
    out[ooff + (long)(orb + ty + i * 8) * out_rs + oc] =
      __float2bfloat16(tile[tx][ty + i * 8]);
}

// ---------------------------------------------------------------------------
__global__ __launch_bounds__(256)
void cast_bf16_k(const float* __restrict__ in, bf16* __restrict__ out, long n)
{
  long i = (long)blockIdx.x * 256 + threadIdx.x;
  long stride = (long)gridDim.x * 256;
  for (; i < n; i += stride) out[i] = __float2bfloat16(in[i]);
}

__global__ __launch_bounds__(256)
void edge_count_k(const int* __restrict__ ei, float* __restrict__ cnt)
{
  int e = blockIdx.x * 256 + threadIdx.x;
  atomicAdd(&cnt[ei[E_ + e]], 1.0f);
}

__global__ __launch_bounds__(256)
void node_prep_k(const float* __restrict__ cnt, float* __restrict__ dinv,
                 float* __restrict__ adjGCNf)
{
  int i = blockIdx.x * 256 + threadIdx.x;
  float dv = rsqrtf(cnt[i] + 1.0f);   // deg includes self-loop
  dinv[i] = dv;
  int gg = i >> 8, li = i & 255;
  atomicAdd(&adjGCNf[((long)gg * 256 + li) * 256 + li], dv * dv);  // self loop
}

__global__ __launch_bounds__(256)
void edge_adj_k(const int* __restrict__ ei, const float* __restrict__ dinv,
                float* __restrict__ adjGCNf, float* __restrict__ adjGINf)
{
  int e = blockIdx.x * 256 + threadIdx.x;
  int src = ei[e], dst = ei[E_ + e];
  int gg = src >> 8;
  int ls = src & 255, ld = dst & 255;
  long idx = ((long)gg * 256 + ld) * 256 + ls;   // [g][dst][src]
  atomicAdd(&adjGINf[idx], 1.0f);
  atomicAdd(&adjGCNf[idx], dinv[src] * dinv[dst]);
}

__global__ __launch_bounds__(256)
void gin_in_k(const float* __restrict__ x, const float* __restrict__ agg,
              bf16* __restrict__ out)
{
  long i = (long)blockIdx.x * 256 + threadIdx.x;
  out[i] = __float2bfloat16(x[i] + agg[i]);
}

// per-column sum / sumsq over 32768 rows of a [N][256] f32 tensor
__global__ __launch_bounds__(256)
void colstats_k(const float* __restrict__ in, float* __restrict__ S,
                float* __restrict__ SSq)
{
  const int d = threadIdx.x;
  const long r0 = (long)blockIdx.x * 128;
  float s = 0.f, ss = 0.f;
  for (int i = 0; i < 128; i++) {
    float v = in[(r0 + i) * 256 + d];
    s += v; ss += v * v;
  }
  atomicAdd(&S[d], s);
  atomicAdd(&SSq[d], ss);
}

// Folds: BN(e0),BN(e1) -> global mean/std(ddof=1) -> 0.5/0.5 mix coefficients.
__global__ __launch_bounds__(256)
void expert_stats_k(const float* __restrict__ S0, const float* __restrict__ SS0,
                    const float* __restrict__ S1, const float* __restrict__ SS1,
                    const float* __restrict__ gkv, const float* __restrict__ bkv,
                    float* __restrict__ kA, float* __restrict__ kB,
                    float* __restrict__ kC)
{
  const int d = threadIdx.x;
  const float invN = 1.0f / 32768.0f;
  float m0 = S0[d] * invN, v0 = SS0[d] * invN - m0 * m0;
  float a0 = gkv[d] * rsqrtf(v0 + 1e-5f), c0 = bkv[d] - m0 * a0;
  float m1 = S1[d] * invN, v1 = SS1[d] * invN - m1 * m1;
  float a1 = gkv[d] * rsqrtf(v1 + 1e-5f), c1 = bkv[d] - m1 * a1;
  float gsum = a0 * S0[d] + 32768.0f * c0 + a1 * S1[d] + 32768.0f * c1;
  float gss  = a0 * a0 * SS0[d] + 2.0f * a0 * c0 * S0[d] + 32768.0f * c0 * c0
             + a1 * a1 * SS1[d] + 2.0f * a1 * c1 * S1[d] + 32768.0f * c1 * c1;
  __shared__ float r1[256], r2[256];
  r1[d] = gsum; r2[d] = gss;
  __syncthreads();
  for (int s = 128; s > 0; s >>= 1) {
    if (d < s) { r1[d] += r1[d + s]; r2[d] += r2[d + s]; }
    __syncthreads();
  }
  const float cnt = 16777216.0f;  // 2*N*D
  float tg = r1[0], tss = r2[0];
  float gm = tg / cnt;
  float var = (tss - tg * tg / cnt) / (cnt - 1.0f);
  float gs = sqrtf(fmaxf(var, 0.f)) + 1e-8f;
  kA[d] = 0.5f * a0 / gs;
  kB[d] = 0.5f * a1 / gs;
  kC[d] = 0.5f * (c0 + c1 - 2.0f * gm) / gs;
}

__global__ __launch_bounds__(256)
void kv_mix_k(const float* __restrict__ hgcn, const float* __restrict__ hgin,
              const float* __restrict__ x, const float* __restrict__ kA,
              const float* __restrict__ kB, const float* __restrict__ kC,
              bf16* __restrict__ kv)
{
  long i = (long)blockIdx.x * 256 + threadIdx.x;
  int d = (int)(i & 255);
  float v = kA[d] * hgcn[i] + kB[d] * hgin[i] + kC[d] + 0.1f * x[i];
  kv[i] = __float2bfloat16(v);
}

template<bool WB>
__global__ __launch_bounds__(256)
void bn_apply_k(const float* __restrict__ in, const float* __restrict__ S,
                const float* __restrict__ SSq, const float* __restrict__ gg,
                const float* __restrict__ bb, float* __restrict__ outf,
                bf16* __restrict__ outb)
{
  long i = (long)blockIdx.x * 256 + threadIdx.x;
  int d = (int)(i & 255);
  const float invN = 1.0f / 32768.0f;
  float m = S[d] * invN;
  float var = SSq[d] * invN - m * m;
  float a = gg[d] * rsqrtf(var + 1e-5f);
  float c = bb[d] - m * a;
  float v = a * in[i] + c;
  outf[i] = v;
  if (WB) outb[i] = __float2bfloat16(v);
}

// ---------------------------------------------------------------------------
// Workspace layout (bytes). Zeroed region first (single memset per call).
// ---------------------------------------------------------------------------
static constexpr size_t OFF_S0 = 0, OFF_SS0 = 1024, OFF_S1 = 2048, OFF_SS1 = 3072;
static constexpr size_t OFF_S2 = 4096, OFF_SS2 = 5120, OFF_S3 = 6144, OFF_SS3 = 7168;
static constexpr size_t OFF_KA = 8192, OFF_KB = 9216, OFF_KC = 10240;
static constexpr size_t OFF_CNT = 16384;                      // N f32
static constexpr size_t ADJ_BYTES = (size_t)B_ * S_ * S_ * 4; // 33554432
static constexpr size_t OFF_ADJGCN = OFF_CNT + 131072;        // f32 adj -> agg -> tbuf
static constexpr size_t OFF_ADJGIN = OFF_ADJGCN + ADJ_BYTES;  // f32 adj -> hgcn -> hbuf
static constexpr size_t ZERO_BYTES = OFF_ADJGIN + ADJ_BYTES;  // 67256320
static constexpr size_t OFF_DINV = ZERO_BYTES;
static constexpr size_t OFF_W = OFF_DINV + 131072;            // bf16 weights, 1703936 B
static constexpr size_t NDB2 = (size_t)N_ * D_ * 2;           // 16777216
static constexpr size_t OFF_ADJGCNB = OFF_W + 1703936;        // bf16 adj -> gin_h -> qhb
static constexpr size_t OFF_ADJGINB = OFF_ADJGCNB + NDB2;     // bf16 adj -> khb
static constexpr size_t OFF_XB   = OFF_ADJGINB + NDB2;        // xb -> vhT
static constexpr size_t OFF_XT   = OFF_XB + NDB2;             // xT -> q1b
static constexpr size_t OFF_XWB  = OFF_XT + NDB2;             // xw_bf -> gin_in -> qb -> hb
static constexpr size_t OFF_XWT  = OFF_XWB + NDB2;            // xwT -> kv_bf
static constexpr size_t OFF_HGIN = OFF_XWT + NDB2;            // f32 hgin -> f1b (bf16 N*512)
static constexpr size_t OFF_VHB  = OFF_HGIN + (size_t)N_ * D_ * 4; // vhb -> ob
static constexpr size_t OFF_T2   = OFF_VHB + NDB2;            // f32 t2

extern "C" void kernel_launch(void* const* d_in, const int* in_sizes, int n_in,
                              void* d_out, int out_size, void* d_ws, size_t ws_size,
                              hipStream_t stream)
{
  (void)in_sizes; (void)n_in; (void)out_size; (void)ws_size;
  const float* x      = (const float*)d_in[0];
  const int*   ei     = (const int*)d_in[1];
  const float* W_gcn  = (const float*)d_in[2];
  const float* b_gcn  = (const float*)d_in[3];
  const float* W_gin1 = (const float*)d_in[4];
  const float* b_gin1 = (const float*)d_in[5];
  const float* W_gin2 = (const float*)d_in[6];
  const float* b_gin2 = (const float*)d_in[7];
  const float* g_kv   = (const float*)d_in[8];
  const float* be_kv  = (const float*)d_in[9];
  const float* Wq1    = (const float*)d_in[10];
  const float* bq1    = (const float*)d_in[11];
  const float* Wq2    = (const float*)d_in[12];
  const float* bq2    = (const float*)d_in[13];
  const float* Wq_a   = (const float*)d_in[14];
  const float* bq_a   = (const float*)d_in[15];
  const float* Wk_a   = (const float*)d_in[16];
  const float* bk_a   = (const float*)d_in[17];
  const float* Wv_a   = (const float*)d_in[18];
  const float* bv_a   = (const float*)d_in[19];
  const float* Wo_a   = (const float*)d_in[20];
  const float* bo_a   = (const float*)d_in[21];
  const float* g_attn = (const float*)d_in[22];
  const float* be_attn= (const float*)d_in[23];
  const float* Wf1    = (const float*)d_in[24];
  const float* bf1    = (const float*)d_in[25];
  const float* Wf2    = (const float*)d_in[26];
  const float* bf2    = (const float*)d_in[27];
  const float* g2     = (const float*)d_in[28];
  const float* be2    = (const float*)d_in[29];

  char* ws = (char*)d_ws;
  float* S0  = (float*)(ws + OFF_S0);  float* SS0 = (float*)(ws + OFF_SS0);
  float* S1  = (float*)(ws + OFF_S1);  float* SS1 = (float*)(ws + OFF_SS1);
  float* S2  = (float*)(ws + OFF_S2);  float* SS2 = (float*)(ws + OFF_SS2);
  float* S3  = (float*)(ws + OFF_S3);  float* SS3 = (float*)(ws + OFF_SS3);
  float* kA  = (float*)(ws + OFF_KA);  float* kB  = (float*)(ws + OFF_KB);
  float* kC  = (float*)(ws + OFF_KC);
  float* cnt = (float*)(ws + OFF_CNT);
  float* adjGCNf = (float*)(ws + OFF_ADJGCN);
  float* adjGINf = (float*)(ws + OFF_ADJGIN);
  float* dinv = (float*)(ws + OFF_DINV);
  bf16* wT = (bf16*)(ws + OFF_W);
  bf16 *WgcnT = wT,            *Wgin1T = wT + 65536,  *Wgin2T = wT + 131072;
  bf16 *Wq1T  = wT + 196608,   *Wq2T   = wT + 262144, *WqaT   = wT + 327680;
  bf16 *WkaT  = wT + 393216,   *WvaT   = wT + 458752, *WoaT   = wT + 524288;
  bf16 *Wf1T  = wT + 589824,   *Wf2T   = wT + 720896;
  bf16* adjGCNb = (bf16*)(ws + OFF_ADJGCNB);
  bf16* adjGINb = (bf16*)(ws + OFF_ADJGINB);
  bf16* xb   = (bf16*)(ws + OFF_XB);
  bf16* xT   = (bf16*)(ws + OFF_XT);
  bf16* xw_bf= (bf16*)(ws + OFF_XWB);
  bf16* xwT  = (bf16*)(ws + OFF_XWT);
  // aliases (lifetime-disjoint)
  float* agg    = adjGCNf;                  // after adj cast
  float* tbuf   = adjGCNf;                  // after gin_in
  float* hgcn   = adjGINf;                  // after adj cast
  float* hbuf   = adjGINf;                  // after kv_mix
  bf16* gin_in  = (bf16*)(ws + OFF_XWB);    // after xw transpose
  bf16* gin_h   = adjGCNb;                  // after GCN agg GEMM
  bf16* qhb     = adjGCNb;                  // after gin2 GEMM
  bf16* khb     = adjGINb;                  // after GIN agg GEMM
  bf16* q1b     = (bf16*)(ws + OFF_XT);     // after GIN agg GEMM
  bf16* qb      = (bf16*)(ws + OFF_XWB);    // after gin1 GEMM
  bf16* hb      = (bf16*)(ws + OFF_XWB);    // after q@Wq_a GEMM
  bf16* kv_bf   = (bf16*)(ws + OFF_XWT);    // after GCN adjacency GEMM
  bf16* vhT     = (bf16*)(ws + OFF_XB);     // after q1 GEMM
  float* hgin   = (float*)(ws + OFF_HGIN);
  bf16* f1b     = (bf16*)(ws + OFF_HGIN);   // after kv_mix
  bf16* vhb     = (bf16*)(ws + OFF_VHB);
  bf16* ob      = (bf16*)(ws + OFF_VHB);    // after vh transpose
  float* t2     = (float*)(ws + OFF_T2);
  float* outp   = (float*)d_out;

  hipMemsetAsync(d_ws, 0, ZERO_BYTES, stream);

  dim3 tb(32, 8);
  // weight transpose+cast: W[K][Nw] f32 -> Wt[Nw][K] bf16
  transpose_cast_k<float><<<dim3(8, 8, 1), tb, 0, stream>>>(W_gcn,  WgcnT,  256, 256, 0, 0, 1, 0);
  transpose_cast_k<float><<<dim3(8, 8, 1), tb, 0, stream>>>(W_gin1, Wgin1T, 256, 256, 0, 0, 1, 0);
  transpose_cast_k<float><<<dim3(8, 8, 1), tb, 0, stream>>>(W_gin2, Wgin2T, 256, 256, 0, 0, 1, 0);
  transpose_cast_k<float><<<dim3(8, 8, 1), tb, 0, stream>>>(Wq1,    Wq1T,   256, 256, 0, 0, 1, 0);
  transpose_cast_k<float><<<dim3(8, 8, 1), tb, 0, stream>>>(Wq2,    Wq2T,   256, 256, 0, 0, 1, 0);
  transpose_cast_k<float><<<dim3(8, 8, 1), tb, 0, stream>>>(Wq_a,   WqaT,   256, 256, 0, 0, 1, 0);
  transpose_cast_k<float><<<dim3(8, 8, 1), tb, 0, stream>>>(Wk_a,   WkaT,   256, 256, 0, 0, 1, 0);
  transpose_cast_k<float><<<dim3(8, 8, 1), tb, 0, stream>>>(Wv_a,   WvaT,   256, 256, 0, 0, 1, 0);
  transpose_cast_k<float><<<dim3(8, 8, 1), tb, 0, stream>>>(Wo_a,   WoaT,   256, 256, 0, 0, 1, 0);
  transpose_cast_k<float><<<dim3(16, 8, 1), tb, 0, stream>>>(Wf1,   Wf1T,   512, 256, 0, 0, 1, 0);
  transpose_cast_k<float><<<dim3(8, 16, 1), tb, 0, stream>>>(Wf2,   Wf2T,   256, 512, 0, 0, 1, 0);
  // x casts
  cast_bf16_k<<<2048, 256, 0, stream>>>(x, xb, (long)N_ * D_);
  transpose_cast_k<float><<<dim3(8, 8, 128), tb, 0, stream>>>(x, xT, 256, 256, 65536, 0, 1, 65536);
  // graph prep
  edge_count_k<<<2048, 256, 0, stream>>>(ei, cnt);
  node_prep_k<<<128, 256, 0, stream>>>(cnt, dinv, adjGCNf);
  edge_adj_k<<<2048, 256, 0, stream>>>(ei, dinv, adjGCNf, adjGINf);
  cast_bf16_k<<<2048, 256, 0, stream>>>(adjGCNf, adjGCNb, (long)B_ * S_ * S_);
  cast_bf16_k<<<2048, 256, 0, stream>>>(adjGINf, adjGINb, (long)B_ * S_ * S_);
  // xw = x @ W_gcn (bf16 out), transpose per graph
  gemm_bt<16><<<dim3(256, 2, 1), 256, 0, stream>>>(xb, WgcnT, nullptr, nullptr, nullptr, xw_bf,
                                                   N_, 256, 256, 0, 0, 0);
  transpose_cast_k<bf16><<<dim3(8, 8, 128), tb, 0, stream>>>(xw_bf, xwT, 256, 256, 65536, 0, 1, 65536);
  // h_gcn = AdjGCN @ xw + b_gcn (batched per graph)
  gemm_bt<10><<<dim3(2, 2, 128), 256, 0, stream>>>(adjGCNb, xwT, b_gcn, nullptr, hgcn, nullptr,
                                                   256, 256, 256, 65536, 65536, 65536);
  // agg = AdjGIN @ x
  gemm_bt<8><<<dim3(2, 2, 128), 256, 0, stream>>>(adjGINb, xT, nullptr, nullptr, agg, nullptr,
                                                  256, 256, 256, 65536, 65536, 65536);
  gin_in_k<<<32768, 256, 0, stream>>>(x, agg, gin_in);
  colstats_k<<<256, 256, 0, stream>>>(hgcn, S0, SS0);
  // GIN MLP
  gemm_bt<19><<<dim3(256, 2, 1), 256, 0, stream>>>(gin_in, Wgin1T, b_gin1, nullptr, nullptr, gin_h,
                                                   N_, 256, 256, 0, 0, 0);
  gemm_bt<10><<<dim3(256, 2, 1), 256, 0, stream>>>(gin_h, Wgin2T, b_gin2, nullptr, hgin, nullptr,
                                                   N_, 256, 256, 0, 0, 0);
  colstats_k<<<256, 256, 0, stream>>>(hgin, S1, SS1);
  expert_stats_k<<<1, 256, 0, stream>>>(S0, SS0, S1, SS1, g_kv, be_kv, kA, kB, kC);
  kv_mix_k<<<32768, 256, 0, stream>>>(hgcn, hgin, x, kA, kB, kC, kv_bf);
  // q MLP + projections
  gemm_bt<19><<<dim3(256, 2, 1), 256, 0, stream>>>(xb, Wq1T, bq1, nullptr, nullptr, q1b,
                                                   N_, 256, 256, 0, 0, 0);
  gemm_bt<18><<<dim3(256, 2, 1), 256, 0, stream>>>(q1b, Wq2T, bq2, nullptr, nullptr, qb,
                                                   N_, 256, 256, 0, 0, 0);
  gemm_bt<18><<<dim3(256, 2, 1), 256, 0, stream>>>(qb, WqaT, bq_a, nullptr, nullptr, qhb,
                                                   N_, 256, 256, 0, 0, 0);
  gemm_bt<18><<<dim3(256, 2, 1), 256, 0, stream>>>(kv_bf, WkaT, bk_a, nullptr, nullptr, khb,
                                                   N_, 256, 256, 0, 0, 0);
  gemm_bt<18><<<dim3(256, 2, 1), 256, 0, stream>>>(kv_bf, WvaT, bv_a, nullptr, nullptr, vhb,
                                                   N_, 256, 256, 0, 0, 0);
  // V transpose per (b,h): [256 s][32 dh] -> [32 dh][256 s]
  transpose_cast_k<bf16><<<dim3(1, 8, 1024), tb, 0, stream>>>(vhb, vhT, 256, 256, 65536, 32, 8, 8192);
  attn_k<<<dim3(4, 8, 128), 256, 0, stream>>>(qhb, khb, vhT, ob);
  // t = x + o @ Wo_a + bo_a
  gemm_bt<14><<<dim3(256, 2, 1), 256, 0, stream>>>(ob, WoaT, bo_a, x, tbuf, nullptr,
                                                   N_, 256, 256, 0, 0, 0);
  colstats_k<<<256, 256, 0, stream>>>(tbuf, S2, SS2);
  bn_apply_k<true><<<32768, 256, 0, stream>>>(tbuf, S2, SS2, g_attn, be_attn, hbuf, hb);
  // FFN
  gemm_bt<19><<<dim3(256, 4, 1), 256, 0, stream>>>(hb, Wf1T, bf1, nullptr, nullptr, f1b,
                                                   N_, 512, 256, 0, 0, 0);
  gemm_bt<14><<<dim3(256, 2, 1), 256, 0, stream>>>(f1b, Wf2T, bf2, hbuf, t2, nullptr,
                                                   N_, 256, 512, 0, 0, 0);
  colstats_k<<<256, 256, 0, stream>>>(t2, S3, SS3);
  bn_apply_k<false><<<32768, 256, 0, stream>>>(t2, S3, SS3, g2, be2, outp, nullptr);
}

// Round 2
// 377.736 us; speedup vs baseline: 1.4205x; 1.4205x over previous
//
#include <hip/hip_runtime.h>
#include <hip/hip_bf16.h>

typedef __hip_bfloat16 bf16;
typedef __attribute__((ext_vector_type(8))) short short8;   // 8 bf16
typedef __attribute__((ext_vector_type(4))) short short4v;  // 4 bf16
typedef __attribute__((ext_vector_type(4))) float f32x4;

#define N_ 32768
#define D_ 256
#define S_ 256
#define B_ 128
#define E_ 524288

static __device__ __forceinline__ f32x4 mfma16(short8 a, short8 b, f32x4 c) {
  return __builtin_amdgcn_mfma_f32_16x16x32_bf16(a, b, c, 0, 0, 0);
}
static __device__ __forceinline__ f32x4 fzero4() {
  f32x4 z; z[0] = 0.f; z[1] = 0.f; z[2] = 0.f; z[3] = 0.f; return z;
}
static __device__ __forceinline__ float bits2f(short s) {
  unsigned u = ((unsigned)(unsigned short)s) << 16;
  return __builtin_bit_cast(float, u);
}
static __device__ __forceinline__ short f2bits(float f) {
  bf16 b = __float2bfloat16(f);
  return __builtin_bit_cast(short, b);
}
static __device__ __forceinline__ float tof(float x) { return x; }
static __device__ __forceinline__ float tof(bf16 x) { return __bfloat162float(x); }

#define GLOAD_LDS16(G, L) __builtin_amdgcn_global_load_lds( \
    (const __attribute__((address_space(1))) void*)(G),     \
    (__attribute__((address_space(3))) void*)(L), 16, 0, 0)

// ---------------------------------------------------------------------------
// bf16 MFMA GEMM, m97 structure: 128x128 tile, BK=32, linear LDS [128][32],
// global_load_lds width-16 staging (wave-uniform LDS base + lane*16).
// A: [M][K] bf16 row-major.  Bt: [Nc][K] bf16 row-major.
// Flags: 1=relu, 2=bias, 4=resid f32, 8=out f32, 16=out bf16, 32=colstats,
//        64=resid bf16.  resid indexed with the same z*bsC offset as C.
// ---------------------------------------------------------------------------
template<int F>
__global__ __launch_bounds__(256)
void gemm_bt(const bf16* __restrict__ A, const bf16* __restrict__ Bt,
             const float* __restrict__ bias, const void* __restrict__ resid,
             float* __restrict__ Cf, bf16* __restrict__ Cb,
             float* __restrict__ Sp, float* __restrict__ SSp,
             int M, int Nc, int K, long bsA, long bsB, long bsC)
{
  __shared__ __align__(16) bf16 lA[128 * 32];
  __shared__ __align__(16) bf16 lB[128 * 32];
  __shared__ float sS[2][128], sSS[2][128];
  const int z = blockIdx.z;
  const bf16* Ab = A + (long)z * bsA;
  const bf16* Bb = Bt + (long)z * bsB;
  const int m0 = blockIdx.x * 128, n0 = blockIdx.y * 128;
  const int tid = threadIdx.x;
  const int lane = tid & 63;
  const int w = tid >> 6, wr = w >> 1, wc = w & 1;
  const int g = lane >> 4, r = lane & 15, ko = g * 8;
  const int srow = lane >> 2, skw = (lane & 3) * 8;   // staging: 16B per lane

  f32x4 acc[4][4];
  for (int i = 0; i < 4; i++) for (int j = 0; j < 4; j++) acc[i][j] = fzero4();

  for (int k0 = 0; k0 < K; k0 += 32) {
    __syncthreads();   // previous iteration's LDS reads complete
    // wave w stages chunks {2w, 2w+1} of A and of B (16 rows x 32 cols each)
    for (int i = 0; i < 2; i++) {
      const int c = w * 2 + i;
      GLOAD_LDS16(Ab + (long)(m0 + c * 16 + srow) * K + k0 + skw, lA + c * 512);
      GLOAD_LDS16(Bb + (long)(n0 + c * 16 + srow) * K + k0 + skw, lB + c * 512);
    }
    __syncthreads();   // vmcnt(0) drain + barrier: tiles ready
    short8 af[4], bfv[4];
    for (int mi = 0; mi < 4; mi++)
      af[mi] = *(const short8*)&lA[(wr * 64 + mi * 16 + r) * 32 + ko];
    for (int ni = 0; ni < 4; ni++)
      bfv[ni] = *(const short8*)&lB[(wc * 64 + ni * 16 + r) * 32 + ko];
    for (int mi = 0; mi < 4; mi++)
      for (int ni = 0; ni < 4; ni++)
        acc[mi][ni] = mfma16(af[mi], bfv[ni], acc[mi][ni]);
  }

  float cs[4] = {0, 0, 0, 0}, css[4] = {0, 0, 0, 0};
  for (int mi = 0; mi < 4; mi++) for (int ni = 0; ni < 4; ni++) {
    const int row = m0 + wr * 64 + mi * 16 + g * 4;   // C/D: row=(lane>>4)*4+reg
    const int col = n0 + wc * 64 + ni * 16 + r;       //      col=lane&15
    float bv = (F & 2) ? bias[col] : 0.0f;
    for (int j = 0; j < 4; j++) {
      long idx = (long)(row + j) * Nc + col;
      float v = acc[mi][ni][j] + bv;
      if (F & 4)  v += ((const float*)resid)[(long)z * bsC + idx];
      if (F & 64) v += bits2f(((const short*)resid)[(long)z * bsC + idx]);
      if (F & 1)  v = fmaxf(v, 0.0f);
      if (F & 32) { cs[ni] += v; css[ni] += v * v; }
      if (F & 8)  Cf[(long)z * bsC + idx] = v;
      if (F & 16) Cb[(long)z * bsC + idx] = __float2bfloat16(v);
    }
  }
  if (F & 32) {
    for (int ni = 0; ni < 4; ni++) {
      cs[ni]  += __shfl_xor(cs[ni], 16);  cs[ni]  += __shfl_xor(cs[ni], 32);
      css[ni] += __shfl_xor(css[ni], 16); css[ni] += __shfl_xor(css[ni], 32);
    }
    if (lane < 16) {
      for (int ni = 0; ni < 4; ni++) {
        sS[wr][wc * 64 + ni * 16 + lane]  = cs[ni];
        sSS[wr][wc * 64 + ni * 16 + lane] = css[ni];
      }
    }
    __syncthreads();
    if (tid < 128) {
      atomicAdd(&Sp[n0 + tid],  sS[0][tid] + sS[1][tid]);
      atomicAdd(&SSp[n0 + tid], sSS[0][tid] + sSS[1][tid]);
    }
  }
}

// ---------------------------------------------------------------------------
// Fused attention with in-kernel V transpose. One block per (qtile=64, h, b).
// qh,kh,vh: [N][256] bf16 (head h at cols h*32..). ob: [N][256] bf16.
// ---------------------------------------------------------------------------
__global__ __launch_bounds__(256)
void attn_k(const bf16* __restrict__ qh, const bf16* __restrict__ kh,
            const bf16* __restrict__ vh, bf16* __restrict__ ob)
{
  const int qt = blockIdx.x, h = blockIdx.y, b = blockIdx.z;
  const int tid = threadIdx.x, lane = tid & 63, w = tid >> 6;
  const int g = lane >> 4, r = lane & 15, ko = g * 8;
  __shared__ __align__(16) bf16 lQ[64 * 40];
  __shared__ __align__(16) bf16 lK[256 * 40];
  __shared__ __align__(16) bf16 lV[32 * 264];
  __shared__ __align__(16) bf16 lP[4][16 * 264];

  { int row = tid >> 2, c = (tid & 3) * 8;
    *(short8*)&lQ[row * 40 + c] =
      *(const short8*)(qh + (long)(b * 256 + qt * 64 + row) * 256 + h * 32 + c); }
  for (int i = 0; i < 4; i++) {
    int s = tid + i * 256; int row = s >> 2, c = (s & 3) * 8;
    *(short8*)&lK[row * 40 + c] =
      *(const short8*)(kh + (long)(b * 256 + row) * 256 + h * 32 + c);
  }
  // V: read [s][dh] slice, write LDS transposed [dh][s]
  const bf16* vbp = vh + (long)b * 65536 + h * 32;
  for (int i = 0; i < 4; i++) {
    int q = tid + i * 256;          // 0..1023
    int s = q >> 2, part = q & 3;   // part: 8 dh each
    short8 v = *(const short8*)(vbp + (long)s * 256 + part * 8);
    for (int j = 0; j < 8; j++)
      ((short*)lV)[(part * 8 + j) * 264 + s] = v[j];
  }
  __syncthreads();

  short8 aq = *(const short8*)&lQ[(w * 16 + r) * 40 + ko];
  f32x4 sc[16];
  for (int nc = 0; nc < 16; nc++) {
    short8 bk = *(const short8*)&lK[(nc * 16 + r) * 40 + ko];
    sc[nc] = mfma16(aq, bk, fzero4());
  }
  const float scale = 0.17677669529663687f;  // 1/sqrt(32)
  float rsum[4];
  for (int j = 0; j < 4; j++) {
    float mx = -3.4e38f;
    for (int nc = 0; nc < 16; nc++) mx = fmaxf(mx, sc[nc][j]);
    mx = fmaxf(mx, __shfl_xor(mx, 1));
    mx = fmaxf(mx, __shfl_xor(mx, 2));
    mx = fmaxf(mx, __shfl_xor(mx, 4));
    mx = fmaxf(mx, __shfl_xor(mx, 8));
    float sum = 0.f;
    for (int nc = 0; nc < 16; nc++) {
      float p = __expf((sc[nc][j] - mx) * scale);
      sc[nc][j] = p; sum += p;
    }
    sum += __shfl_xor(sum, 1); sum += __shfl_xor(sum, 2);
    sum += __shfl_xor(sum, 4); sum += __shfl_xor(sum, 8);
    rsum[j] = sum;
    for (int nc = 0; nc < 16; nc++)
      lP[w][(g * 4 + j) * 264 + nc * 16 + r] = __float2bfloat16(sc[nc][j]);
  }
  __syncthreads();
  f32x4 oa[2]; oa[0] = fzero4(); oa[1] = fzero4();
  for (int kc = 0; kc < 8; kc++) {
    short8 ap = *(const short8*)&lP[w][r * 264 + kc * 32 + ko];
    for (int n = 0; n < 2; n++) {
      short8 bv = *(const short8*)&lV[(n * 16 + r) * 264 + kc * 32 + ko];
      oa[n] = mfma16(ap, bv, oa[n]);
    }
  }
  for (int n = 0; n < 2; n++) for (int j = 0; j < 4; j++) {
    float v = oa[n][j] / rsum[j];
    ob[(long)(b * 256 + qt * 64 + w * 16 + g * 4 + j) * 256 + h * 32 + n * 16 + r] =
      __float2bfloat16(v);
  }
}

// ---------------------------------------------------------------------------
// Transposes
// ---------------------------------------------------------------------------
template<typename TIN>
__global__ __launch_bounds__(256)
void transpose_cast_k(const TIN* __restrict__ in, bf16* __restrict__ out,
                      int in_rs, int out_rs, long zhi, long out_zs)
{
  __shared__ float tile[32][33];
  const int z = blockIdx.z;
  const long ioff = (long)z * zhi;
  const long ooff = (long)z * out_zs;
  const int tx = threadIdx.x, ty = threadIdx.y;
  const int c = blockIdx.x * 32 + tx;
  const int rb = blockIdx.y * 32;
  for (int i = 0; i < 4; i++)
    tile[ty + i * 8][tx] = tof(in[ioff + (long)(rb + ty + i * 8) * in_rs + c]);
  __syncthreads();
  const int oc = rb + tx;
  const int orb = blockIdx.x * 32;
  for (int i = 0; i < 4; i++)
    out[ooff + (long)(orb + ty + i * 8) * out_rs + oc] =
      __float2bfloat16(tile[tx][ty + i * 8]);
}

// all nine 256x256 weight transposes in one launch (grid z = weight id)
__global__ __launch_bounds__(256)
void w9t_k(const float* w0, const float* w1, const float* w2, const float* w3,
           const float* w4, const float* w5, const float* w6, const float* w7,
           const float* w8, bf16* __restrict__ out)
{
  __shared__ float tile[32][33];
  const float* srcs[9] = {w0, w1, w2, w3, w4, w5, w6, w7, w8};
  const int wi = blockIdx.z;
  const float* in = srcs[wi];
  bf16* o = out + (long)wi * 65536;
  const int tx = threadIdx.x, ty = threadIdx.y;
  const int c = blockIdx.x * 32 + tx;
  const int rb = blockIdx.y * 32;
  for (int i = 0; i < 4; i++)
    tile[ty + i * 8][tx] = in[(rb + ty + i * 8) * 256 + c];
  __syncthreads();
  const int oc = rb + tx;
  const int orb = blockIdx.x * 32;
  for (int i = 0; i < 4; i++)
    o[(orb + ty + i * 8) * 256 + oc] = __float2bfloat16(tile[tx][ty + i * 8]);
}

// ---------------------------------------------------------------------------
// Elementwise / graph kernels
// ---------------------------------------------------------------------------
__global__ __launch_bounds__(256)
void cast4_k(const float* __restrict__ in, bf16* __restrict__ out)
{
  long i = ((long)blockIdx.x * 256 + threadIdx.x) * 4;
  float4 v = *(const float4*)(in + i);
  short4v o;
  o[0] = f2bits(v.x); o[1] = f2bits(v.y); o[2] = f2bits(v.z); o[3] = f2bits(v.w);
  *(short4v*)(out + i) = o;
}

__global__ __launch_bounds__(256)
void edge_cnt_k(const int* __restrict__ ei, float* __restrict__ cnt)
{
  int e = blockIdx.x * 256 + threadIdx.x;
  int src = ei[e], dst = ei[E_ + e];
  long idx = ((long)(src >> 8) * 256 + (dst & 255)) * 256 + (src & 255); // [g][dst][src]
  atomicAdd(&cnt[idx], 1.0f);
}

// deg from row-sums of cnt (+1 self loop) -> dinv. 16 lanes per row.
__global__ __launch_bounds__(256)
void deg_k(const float* __restrict__ cnt, float* __restrict__ dinv)
{
  int rid = blockIdx.x * 16 + (threadIdx.x >> 4);
  int l16 = threadIdx.x & 15;
  const float4* rp = (const float4*)(cnt + (long)rid * 256);
  float s = 0.f;
  for (int i = 0; i < 4; i++) {
    float4 v = rp[l16 + i * 16];
    s += v.x + v.y + v.z + v.w;
  }
  s += __shfl_xor(s, 1); s += __shfl_xor(s, 2);
  s += __shfl_xor(s, 4); s += __shfl_xor(s, 8);
  if (l16 == 0) dinv[rid] = rsqrtf(s + 1.0f);
}

// derive both bf16 adjacencies from counts + dinv (+ GCN diagonal self-loop)
__global__ __launch_bounds__(256)
void adj_derive_k(const float* __restrict__ cnt, const float* __restrict__ dinv,
                  bf16* __restrict__ gin, bf16* __restrict__ gcn)
{
  long i = ((long)blockIdx.x * 256 + threadIdx.x) * 4;
  float4 c = *(const float4*)(cnt + i);
  long row = i >> 8;            // g*256 + dst
  int g = (int)(row >> 8), dst = (int)(row & 255);
  int src0 = (int)(i & 255);
  float dd = dinv[row];
  const float* ds = dinv + (long)g * 256 + src0;
  float cv[4] = {c.x, c.y, c.z, c.w};
  short4v oi, oc;
  for (int j = 0; j < 4; j++) {
    float gv = cv[j] * dd * ds[j];
    if (src0 + j == dst) gv += dd * dd;
    oi[j] = f2bits(cv[j]);
    oc[j] = f2bits(gv);
  }
  *(short4v*)(gin + i) = oi;
  *(short4v*)(gcn + i) = oc;
}

// BN(e0),BN(e1) stats -> global mean/std(ddof=1) -> mix coefficients
__global__ __launch_bounds__(256)
void expert_stats_k(const float* __restrict__ S0, const float* __restrict__ SS0,
                    const float* __restrict__ S1, const float* __restrict__ SS1,
                    const float* __restrict__ gkv, const float* __restrict__ bkv,
                    float* __restrict__ kA, float* __restrict__ kB,
                    float* __restrict__ kC)
{
  const int d = threadIdx.x;
  const float invN = 1.0f / 32768.0f;
  float m0 = S0[d] * invN, v0 = SS0[d] * invN - m0 * m0;
  float a0 = gkv[d] * rsqrtf(v0 + 1e-5f), c0 = bkv[d] - m0 * a0;
  float m1 = S1[d] * invN, v1 = SS1[d] * invN - m1 * m1;
  float a1 = gkv[d] * rsqrtf(v1 + 1e-5f), c1 = bkv[d] - m1 * a1;
  float gsum = a0 * S0[d] + 32768.0f * c0 + a1 * S1[d] + 32768.0f * c1;
  float gss  = a0 * a0 * SS0[d] + 2.0f * a0 * c0 * S0[d] + 32768.0f * c0 * c0
             + a1 * a1 * SS1[d] + 2.0f * a1 * c1 * S1[d] + 32768.0f * c1 * c1;
  __shared__ float r1[256], r2[256];
  r1[d] = gsum; r2[d] = gss;
  __syncthreads();
  for (int s = 128; s > 0; s >>= 1) {
    if (d < s) { r1[d] += r1[d + s]; r2[d] += r2[d + s]; }
    __syncthreads();
  }
  const float cntall = 16777216.0f;  // 2*N*D
  float tg = r1[0], tss = r2[0];
  float gm = tg / cntall;
  float var = (tss - tg * tg / cntall) / (cntall - 1.0f);
  float gs = sqrtf(fmaxf(var, 0.f)) + 1e-8f;
  kA[d] = 0.5f * a0 / gs;
  kB[d] = 0.5f * a1 / gs;
  kC[d] = 0.5f * (c0 + c1 - 2.0f * gm) / gs;
}

__global__ __launch_bounds__(256)
void kv_mix_k(const bf16* __restrict__ hgcn, const bf16* __restrict__ hgin,
              const bf16* __restrict__ xb, const float* __restrict__ kA,
              const float* __restrict__ kB, const float* __restrict__ kC,
              bf16* __restrict__ kv)
{
  long i = ((long)blockIdx.x * 256 + threadIdx.x) * 8;
  int d0 = (int)(i & 255);
  short8 a = *(const short8*)(hgcn + i);
  short8 b = *(const short8*)(hgin + i);
  short8 c = *(const short8*)(xb + i);
  short8 o;
  for (int j = 0; j < 8; j++) {
    int d = d0 + j;
    float v = kA[d] * bits2f(a[j]) + kB[d] * bits2f(b[j]) + kC[d] + 0.1f * bits2f(c[j]);
    o[j] = f2bits(v);
  }
  *(short8*)(kv + i) = o;
}

// MODE: 1 = write f32, 2 = write bf16
template<int MODE>
__global__ __launch_bounds__(256)
void bn_apply_k(const bf16* __restrict__ in, const float* __restrict__ S,
                const float* __restrict__ SSq, const float* __restrict__ gg,
                const float* __restrict__ bb, float* __restrict__ outf,
                bf16* __restrict__ outb)
{
  long i = ((long)blockIdx.x * 256 + threadIdx.x) * 8;
  int d0 = (int)(i & 255);
  short8 v = *(const short8*)(in + i);
  const float invN = 1.0f / 32768.0f;
  float4 o0, o1; short8 o8;
  for (int j = 0; j < 8; j++) {
    int d = d0 + j;
    float m = S[d] * invN;
    float var = SSq[d] * invN - m * m;
    float a = gg[d] * rsqrtf(var + 1e-5f);
    float c = bb[d] - m * a;
    float o = a * bits2f(v[j]) + c;
    if (MODE & 1) { if (j < 4) (&o0.x)[j] = o; else (&o1.x)[j - 4] = o; }
    if (MODE & 2) o8[j] = f2bits(o);
  }
  if (MODE & 1) { *(float4*)(outf + i) = o0; *(float4*)(outf + i + 4) = o1; }
  if (MODE & 2) *(short8*)(outb + i) = o8;
}

// ---------------------------------------------------------------------------
// Workspace layout (bytes)
// ---------------------------------------------------------------------------
static constexpr size_t OFF_S0 = 0, OFF_SS0 = 1024, OFF_S1 = 2048, OFF_SS1 = 3072;
static constexpr size_t OFF_S2 = 4096, OFF_SS2 = 5120, OFF_S3 = 6144, OFF_SS3 = 7168;
static constexpr size_t OFF_KA = 8192, OFF_KB = 9216, OFF_KC = 10240;
static constexpr size_t OFF_CNT = 16384;                       // f32 counts [B][S][S]
static constexpr size_t ADJ_BYTES = (size_t)B_ * S_ * S_ * 4;  // 33554432
static constexpr size_t ZERO_BYTES = OFF_CNT + ADJ_BYTES;      // memset region
static constexpr size_t OFF_DINV = ZERO_BYTES;                 // 131072
static constexpr size_t OFF_W = OFF_DINV + 131072;             // bf16 weights 1703936
static constexpr size_t NDB2 = (size_t)N_ * D_ * 2;            // 16777216
static constexpr size_t OFF_ADJGINB = OFF_W + 1703936;
static constexpr size_t OFF_ADJGCNB = OFF_ADJGINB + NDB2;
static constexpr size_t OFF_XB   = OFF_ADJGCNB + NDB2;
static constexpr size_t OFF_XT   = OFF_XB + NDB2;
static constexpr size_t OFF_XWB  = OFF_XT + NDB2;
static constexpr size_t OFF_XWT  = OFF_XWB + NDB2;   // f1b spans XWT+KV (33.5MB)
static constexpr size_t OFF_KV   = OFF_XWT + NDB2;
static constexpr size_t OFF_HGCN = OFF_KV + NDB2;
static constexpr size_t OFF_HGIN = OFF_HGCN + NDB2;

extern "C" void kernel_launch(void* const* d_in, const int* in_sizes, int n_in,
                              void* d_out, int out_size, void* d_ws, size_t ws_size,
                              hipStream_t stream)
{
  (void)in_sizes; (void)n_in; (void)out_size; (void)ws_size;
  const float* x      = (const float*)d_in[0];
  const int*   ei     = (const int*)d_in[1];
  const float* W_gcn  = (const float*)d_in[2];
  const float* b_gcn  = (const float*)d_in[3];
  const float* W_gin1 = (const float*)d_in[4];
  const float* b_gin1 = (const float*)d_in[5];
  const float* W_gin2 = (const float*)d_in[6];
  const float* b_gin2 = (const float*)d_in[7];
  const float* g_kv   = (const float*)d_in[8];
  const float* be_kv  = (const float*)d_in[9];
  const float* Wq1    = (const float*)d_in[10];
  const float* bq1    = (const float*)d_in[11];
  const float* Wq2    = (const float*)d_in[12];
  const float* bq2    = (const float*)d_in[13];
  const float* Wq_a   = (const float*)d_in[14];
  const float* bq_a   = (const float*)d_in[15];
  const float* Wk_a   = (const float*)d_in[16];
  const float* bk_a   = (const float*)d_in[17];
  const float* Wv_a   = (const float*)d_in[18];
  const float* bv_a   = (const float*)d_in[19];
  const float* Wo_a   = (const float*)d_in[20];
  const float* bo_a   = (const float*)d_in[21];
  const float* g_attn = (const float*)d_in[22];
  const float* be_attn= (const float*)d_in[23];
  const float* Wf1    = (const float*)d_in[24];
  const float* bf1    = (const float*)d_in[25];
  const float* Wf2    = (const float*)d_in[26];
  const float* bf2    = (const float*)d_in[27];
  const float* g2     = (const float*)d_in[28];
  const float* be2    = (const float*)d_in[29];

  char* ws = (char*)d_ws;
  float* S0  = (float*)(ws + OFF_S0);  float* SS0 = (float*)(ws + OFF_SS0);
  float* S1  = (float*)(ws + OFF_S1);  float* SS1 = (float*)(ws + OFF_SS1);
  float* S2  = (float*)(ws + OFF_S2);  float* SS2 = (float*)(ws + OFF_SS2);
  float* S3  = (float*)(ws + OFF_S3);  float* SS3 = (float*)(ws + OFF_SS3);
  float* kA  = (float*)(ws + OFF_KA);  float* kB  = (float*)(ws + OFF_KB);
  float* kC  = (float*)(ws + OFF_KC);
  float* cntA = (float*)(ws + OFF_CNT);
  float* dinv = (float*)(ws + OFF_DINV);
  bf16* wT = (bf16*)(ws + OFF_W);
  bf16 *WgcnT = wT,            *Wgin1T = wT + 65536,  *Wgin2T = wT + 131072;
  bf16 *Wq1T  = wT + 196608,   *Wq2T   = wT + 262144, *WqaT   = wT + 327680;
  bf16 *WkaT  = wT + 393216,   *WvaT   = wT + 458752, *WoaT   = wT + 524288;
  bf16 *Wf1T  = wT + 589824,   *Wf2T   = wT + 720896;
  bf16* adjGINb = (bf16*)(ws + OFF_ADJGINB);
  bf16* adjGCNb = (bf16*)(ws + OFF_ADJGCNB);
  bf16* xb    = (bf16*)(ws + OFF_XB);
  bf16* xT    = (bf16*)(ws + OFF_XT);
  bf16* xw_bf = (bf16*)(ws + OFF_XWB);
  bf16* xwT   = (bf16*)(ws + OFF_XWT);
  bf16* kv_bf = (bf16*)(ws + OFF_KV);
  bf16* hgcnb = (bf16*)(ws + OFF_HGCN);
  bf16* hginb = (bf16*)(ws + OFF_HGIN);
  // lifetime-disjoint aliases
  bf16* gin_in = xw_bf;                    // after xw transposed
  bf16* gin_h  = adjGCNb;                  // after GCN-agg GEMM consumed adj
  bf16* qhb    = adjGCNb;                  // after gin2 GEMM consumed gin_h
  bf16* khb    = adjGINb;                  // after GIN-agg GEMM consumed adj
  bf16* q1b    = xT;                       // after GIN-agg GEMM consumed xT
  bf16* qb     = xw_bf;                    // after gin1 consumed gin_in
  bf16* vhb    = hgcnb;                    // after kv_mix consumed hgcn
  bf16* ob     = hginb;                    // after kv_mix consumed hgin
  bf16* tbufb  = (bf16*)(ws + OFF_CNT);    // after adj_derive consumed cnt
  bf16* hb     = xb;                       // after o-GEMM consumed xb resid
  bf16* f1b    = (bf16*)(ws + OFF_XWT);    // spans XWT+KV, after va GEMM
  bf16* t2b    = adjGCNb;                  // after attn consumed qhb
  float* outp  = (float*)d_out;

  hipMemsetAsync(d_ws, 0, ZERO_BYTES, stream);

  dim3 tb(32, 8);
  // weights -> transposed bf16 (one launch for the nine DxD, two for FFN)
  w9t_k<<<dim3(8, 8, 9), tb, 0, stream>>>(W_gcn, W_gin1, W_gin2, Wq1, Wq2,
                                          Wq_a, Wk_a, Wv_a, Wo_a, wT);
  transpose_cast_k<float><<<dim3(16, 8, 1), tb, 0, stream>>>(Wf1, Wf1T, 512, 256, 0, 0);
  transpose_cast_k<float><<<dim3(8, 16, 1), tb, 0, stream>>>(Wf2, Wf2T, 256, 512, 0, 0);
  // x casts
  cast4_k<<<8192, 256, 0, stream>>>(x, xb);
  transpose_cast_k<float><<<dim3(8, 8, 128), tb, 0, stream>>>(x, xT, 256, 256, 65536, 65536);
  // graph prep: one atomic per edge, then clean passes
  edge_cnt_k<<<2048, 256, 0, stream>>>(ei, cntA);
  deg_k<<<2048, 256, 0, stream>>>(cntA, dinv);
  adj_derive_k<<<8192, 256, 0, stream>>>(cntA, dinv, adjGINb, adjGCNb);
  // xw = x @ W_gcn, then per-graph transpose
  gemm_bt<16><<<dim3(256, 2, 1), 256, 0, stream>>>(xb, WgcnT, nullptr, nullptr,
      nullptr, xw_bf, nullptr, nullptr, N_, 256, 256, 0, 0, 0);
  transpose_cast_k<bf16><<<dim3(8, 8, 128), tb, 0, stream>>>(xw_bf, xwT, 256, 256, 65536, 65536);
  // h_gcn = AdjGCN @ xw + b_gcn  [stats S0] -> bf16
  gemm_bt<50><<<dim3(2, 2, 128), 256, 0, stream>>>(adjGCNb, xwT, b_gcn, nullptr,
      nullptr, hgcnb, S0, SS0, 256, 256, 256, 65536, 65536, 65536);
  // gin_in = AdjGIN @ x + x  (resid bf16 = xb) -> bf16
  gemm_bt<80><<<dim3(2, 2, 128), 256, 0, stream>>>(adjGINb, xT, nullptr, xb,
      nullptr, gin_in, nullptr, nullptr, 256, 256, 256, 65536, 65536, 65536);
  // GIN MLP
  gemm_bt<19><<<dim3(256, 2, 1), 256, 0, stream>>>(gin_in, Wgin1T, b_gin1, nullptr,
      nullptr, gin_h, nullptr, nullptr, N_, 256, 256, 0, 0, 0);
  gemm_bt<50><<<dim3(256, 2, 1), 256, 0, stream>>>(gin_h, Wgin2T, b_gin2, nullptr,
      nullptr, hginb, S1, SS1, N_, 256, 256, 0, 0, 0);
  expert_stats_k<<<1, 256, 0, stream>>>(S0, SS0, S1, SS1, g_kv, be_kv, kA, kB, kC);
  kv_mix_k<<<4096, 256, 0, stream>>>(hgcnb, hginb, xb, kA, kB, kC, kv_bf);
  // q MLP + attention projections
  gemm_bt<19><<<dim3(256, 2, 1), 256, 0, stream>>>(xb, Wq1T, bq1, nullptr,
      nullptr, q1b, nullptr, nullptr, N_, 256, 256, 0, 0, 0);
  gemm_bt<18><<<dim3(256, 2, 1), 256, 0, stream>>>(q1b, Wq2T, bq2, nullptr,
      nullptr, qb, nullptr, nullptr, N_, 256, 256, 0, 0, 0);
  gemm_bt<18><<<dim3(256, 2, 1), 256, 0, stream>>>(qb, WqaT, bq_a, nullptr,
      nullptr, qhb, nullptr, nullptr, N_, 256, 256, 0, 0, 0);
  gemm_bt<18><<<dim3(256, 2, 1), 256, 0, stream>>>(kv_bf, WkaT, bk_a, nullptr,
      nullptr, khb, nullptr, nullptr, N_, 256, 256, 0, 0, 0);
  gemm_bt<18><<<dim3(256, 2, 1), 256, 0, stream>>>(kv_bf, WvaT, bv_a, nullptr,
      nullptr, vhb, nullptr, nullptr, N_, 256, 256, 0, 0, 0);
  attn_k<<<dim3(4, 8, 128), 256, 0, stream>>>(qhb, khb, vhb, ob);
  // t = x + o @ Wo_a + bo_a  [stats S2] -> bf16
  gemm_bt<114><<<dim3(256, 2, 1), 256, 0, stream>>>(ob, WoaT, bo_a, xb,
      nullptr, tbufb, S2, SS2, N_, 256, 256, 0, 0, 0);
  bn_apply_k<2><<<4096, 256, 0, stream>>>(tbufb, S2, SS2, g_attn, be_attn, nullptr, hb);
  // FFN
  gemm_bt<19><<<dim3(256, 4, 1), 256, 0, stream>>>(hb, Wf1T, bf1, nullptr,
      nullptr, f1b, nullptr, nullptr, N_, 512, 256, 0, 0, 0);
  gemm_bt<114><<<dim3(256, 2, 1), 256, 0, stream>>>(f1b, Wf2T, bf2, hb,
      nullptr, t2b, S3, SS3, N_, 256, 512, 0, 0, 0);
  bn_apply_k<1><<<4096, 256, 0, stream>>>(t2b, S3, SS3, g2, be2, outp, nullptr);
}

// Round 3
// 354.504 us; speedup vs baseline: 1.5136x; 1.0655x over previous
//
#include <hip/hip_runtime.h>
#include <hip/hip_bf16.h>

typedef __hip_bfloat16 bf16;
typedef __attribute__((ext_vector_type(8))) short short8;   // 8 bf16
typedef __attribute__((ext_vector_type(4))) short short4v;  // 4 bf16
typedef __attribute__((ext_vector_type(4))) float f32x4;

#define N_ 32768
#define D_ 256
#define S_ 256
#define B_ 128
#define E_ 524288

static __device__ __forceinline__ f32x4 mfma16(short8 a, short8 b, f32x4 c) {
  return __builtin_amdgcn_mfma_f32_16x16x32_bf16(a, b, c, 0, 0, 0);
}
static __device__ __forceinline__ f32x4 fzero4() {
  f32x4 z; z[0] = 0.f; z[1] = 0.f; z[2] = 0.f; z[3] = 0.f; return z;
}
static __device__ __forceinline__ float bits2f(short s) {
  unsigned u = ((unsigned)(unsigned short)s) << 16;
  return __builtin_bit_cast(float, u);
}
static __device__ __forceinline__ short f2bits(float f) {
  bf16 b = __float2bfloat16(f);
  return __builtin_bit_cast(short, b);
}
static __device__ __forceinline__ float tof(float x) { return x; }
static __device__ __forceinline__ float tof(bf16 x) { return __bfloat162float(x); }

#define GLOAD_LDS16(G, L) __builtin_amdgcn_global_load_lds( \
    (const __attribute__((address_space(1))) void*)(G),     \
    (__attribute__((address_space(3))) void*)(L), 16, 0, 0)

// ---------------------------------------------------------------------------
// bf16 MFMA GEMM, m97 structure: 128x128 tile, BK=32, linear LDS [128][32],
// global_load_lds width-16 staging (wave-uniform LDS base + lane*16).
// A: [M][K] bf16 row-major.  Bt: [Nc][K] bf16 row-major.
// Flags: 1=relu, 2=bias, 4=resid f32, 8=out f32, 16=out bf16, 32=colstats,
//        64=resid bf16.  resid indexed with the same z*bsC offset as C.
// ---------------------------------------------------------------------------
template<int F>
__global__ __launch_bounds__(256)
void gemm_bt(const bf16* __restrict__ A, const bf16* __restrict__ Bt,
             const float* __restrict__ bias, const void* __restrict__ resid,
             float* __restrict__ Cf, bf16* __restrict__ Cb,
             float* __restrict__ Sp, float* __restrict__ SSp,
             int M, int Nc, int K, long bsA, long bsB, long bsC)
{
  __shared__ __align__(16) bf16 lA[128 * 32];
  __shared__ __align__(16) bf16 lB[128 * 32];
  __shared__ float sS[2][128], sSS[2][128];
  const int z = blockIdx.z;
  const bf16* Ab = A + (long)z * bsA;
  const bf16* Bb = Bt + (long)z * bsB;
  const int m0 = blockIdx.x * 128, n0 = blockIdx.y * 128;
  const int tid = threadIdx.x;
  const int lane = tid & 63;
  const int w = tid >> 6, wr = w >> 1, wc = w & 1;
  const int g = lane >> 4, r = lane & 15, ko = g * 8;
  const int srow = lane >> 2, skw = (lane & 3) * 8;   // staging: 16B per lane

  f32x4 acc[4][4];
  for (int i = 0; i < 4; i++) for (int j = 0; j < 4; j++) acc[i][j] = fzero4();

  for (int k0 = 0; k0 < K; k0 += 32) {
    __syncthreads();   // previous iteration's LDS reads complete
    for (int i = 0; i < 2; i++) {
      const int c = w * 2 + i;
      GLOAD_LDS16(Ab + (long)(m0 + c * 16 + srow) * K + k0 + skw, lA + c * 512);
      GLOAD_LDS16(Bb + (long)(n0 + c * 16 + srow) * K + k0 + skw, lB + c * 512);
    }
    __syncthreads();   // vmcnt(0) drain + barrier: tiles ready
    short8 af[4], bfv[4];
    for (int mi = 0; mi < 4; mi++)
      af[mi] = *(const short8*)&lA[(wr * 64 + mi * 16 + r) * 32 + ko];
    for (int ni = 0; ni < 4; ni++)
      bfv[ni] = *(const short8*)&lB[(wc * 64 + ni * 16 + r) * 32 + ko];
    for (int mi = 0; mi < 4; mi++)
      for (int ni = 0; ni < 4; ni++)
        acc[mi][ni] = mfma16(af[mi], bfv[ni], acc[mi][ni]);
  }

  float cs[4] = {0, 0, 0, 0}, css[4] = {0, 0, 0, 0};
  for (int mi = 0; mi < 4; mi++) for (int ni = 0; ni < 4; ni++) {
    const int row = m0 + wr * 64 + mi * 16 + g * 4;   // C/D: row=(lane>>4)*4+reg
    const int col = n0 + wc * 64 + ni * 16 + r;       //      col=lane&15
    float bv = (F & 2) ? bias[col] : 0.0f;
    for (int j = 0; j < 4; j++) {
      long idx = (long)(row + j) * Nc + col;
      float v = acc[mi][ni][j] + bv;
      if (F & 4)  v += ((const float*)resid)[(long)z * bsC + idx];
      if (F & 64) v += bits2f(((const short*)resid)[(long)z * bsC + idx]);
      if (F & 1)  v = fmaxf(v, 0.0f);
      if (F & 32) { cs[ni] += v; css[ni] += v * v; }
      if (F & 8)  Cf[(long)z * bsC + idx] = v;
      if (F & 16) Cb[(long)z * bsC + idx] = __float2bfloat16(v);
    }
  }
  if (F & 32) {
    for (int ni = 0; ni < 4; ni++) {
      cs[ni]  += __shfl_xor(cs[ni], 16);  cs[ni]  += __shfl_xor(cs[ni], 32);
      css[ni] += __shfl_xor(css[ni], 16); css[ni] += __shfl_xor(css[ni], 32);
    }
    if (lane < 16) {
      for (int ni = 0; ni < 4; ni++) {
        sS[wr][wc * 64 + ni * 16 + lane]  = cs[ni];
        sSS[wr][wc * 64 + ni * 16 + lane] = css[ni];
      }
    }
    __syncthreads();
    if (tid < 128) {
      atomicAdd(&Sp[n0 + tid],  sS[0][tid] + sS[1][tid]);
      atomicAdd(&SSp[n0 + tid], sSS[0][tid] + sSS[1][tid]);
    }
  }
}

// ---------------------------------------------------------------------------
// Fused attention. One block per (h, b); 4 waves; each wave sweeps 64 q-rows
// in 4 chunks of 16. K + transposed V staged once per block (reused by all
// 256 q rows). Q fragments read directly from global. P is per-wave LDS, so
// no block barrier inside the mc loop.
// ---------------------------------------------------------------------------
__global__ __launch_bounds__(256)
void attn_k(const bf16* __restrict__ qh, const bf16* __restrict__ kh,
            const bf16* __restrict__ vh, bf16* __restrict__ ob)
{
  const int h = blockIdx.x, b = blockIdx.y;
  const int tid = threadIdx.x, lane = tid & 63, w = tid >> 6;
  const int g = lane >> 4, r = lane & 15, ko = g * 8;
  __shared__ __align__(16) bf16 lK[256 * 40];
  __shared__ __align__(16) bf16 lV[32 * 264];
  __shared__ __align__(16) bf16 lP[4][16 * 264];

  for (int i = 0; i < 4; i++) {
    int s = tid + i * 256; int row = s >> 2, c = (s & 3) * 8;
    *(short8*)&lK[row * 40 + c] =
      *(const short8*)(kh + (long)(b * 256 + row) * 256 + h * 32 + c);
  }
  // V: read [s][dh] slice, write LDS transposed [dh][s]
  const bf16* vbp = vh + (long)b * 65536 + h * 32;
  for (int i = 0; i < 4; i++) {
    int q = tid + i * 256;          // 0..1023
    int s = q >> 2, part = q & 3;   // part: 8 dh each
    short8 v = *(const short8*)(vbp + (long)s * 256 + part * 8);
    for (int j = 0; j < 8; j++)
      ((short*)lV)[(part * 8 + j) * 264 + s] = v[j];
  }
  __syncthreads();

  const float scale = 0.17677669529663687f;  // 1/sqrt(32)
  for (int mc = 0; mc < 4; mc++) {
    const long qrow = (long)b * 256 + w * 64 + mc * 16;
    short8 aq = *(const short8*)(qh + (qrow + r) * 256 + h * 32 + ko);
    f32x4 sc[16];
    for (int nc = 0; nc < 16; nc++) {
      short8 bk = *(const short8*)&lK[(nc * 16 + r) * 40 + ko];
      sc[nc] = mfma16(aq, bk, fzero4());
    }
    float rsum[4];
    for (int j = 0; j < 4; j++) {
      float mx = -3.4e38f;
      for (int nc = 0; nc < 16; nc++) mx = fmaxf(mx, sc[nc][j]);
      mx = fmaxf(mx, __shfl_xor(mx, 1));
      mx = fmaxf(mx, __shfl_xor(mx, 2));
      mx = fmaxf(mx, __shfl_xor(mx, 4));
      mx = fmaxf(mx, __shfl_xor(mx, 8));
      float sum = 0.f;
      for (int nc = 0; nc < 16; nc++) {
        float p = __expf((sc[nc][j] - mx) * scale);
        sc[nc][j] = p; sum += p;
      }
      sum += __shfl_xor(sum, 1); sum += __shfl_xor(sum, 2);
      sum += __shfl_xor(sum, 4); sum += __shfl_xor(sum, 8);
      rsum[j] = sum;
      for (int nc = 0; nc < 16; nc++)
        lP[w][(g * 4 + j) * 264 + nc * 16 + r] = __float2bfloat16(sc[nc][j]);
    }
    f32x4 oa[2]; oa[0] = fzero4(); oa[1] = fzero4();
    for (int kc = 0; kc < 8; kc++) {
      short8 ap = *(const short8*)&lP[w][r * 264 + kc * 32 + ko];
      for (int n = 0; n < 2; n++) {
        short8 bv = *(const short8*)&lV[(n * 16 + r) * 264 + kc * 32 + ko];
        oa[n] = mfma16(ap, bv, oa[n]);
      }
    }
    for (int n = 0; n < 2; n++) for (int j = 0; j < 4; j++) {
      float v = oa[n][j] / rsum[j];
      ob[(qrow + g * 4 + j) * 256 + h * 32 + n * 16 + r] = __float2bfloat16(v);
    }
  }
}

// ---------------------------------------------------------------------------
// Transposes
// ---------------------------------------------------------------------------
template<typename TIN>
__global__ __launch_bounds__(256)
void transpose_cast_k(const TIN* __restrict__ in, bf16* __restrict__ out,
                      int in_rs, int out_rs, long zhi, long out_zs)
{
  __shared__ float tile[32][33];
  const int z = blockIdx.z;
  const long ioff = (long)z * zhi;
  const long ooff = (long)z * out_zs;
  const int tx = threadIdx.x, ty = threadIdx.y;
  const int c = blockIdx.x * 32 + tx;
  const int rb = blockIdx.y * 32;
  for (int i = 0; i < 4; i++)
    tile[ty + i * 8][tx] = tof(in[ioff + (long)(rb + ty + i * 8) * in_rs + c]);
  __syncthreads();
  const int oc = rb + tx;
  const int orb = blockIdx.x * 32;
  for (int i = 0; i < 4; i++)
    out[ooff + (long)(orb + ty + i * 8) * out_rs + oc] =
      __float2bfloat16(tile[tx][ty + i * 8]);
}

// all nine 256x256 weight transposes in one launch (grid z = weight id)
__global__ __launch_bounds__(256)
void w9t_k(const float* w0, const float* w1, const float* w2, const float* w3,
           const float* w4, const float* w5, const float* w6, const float* w7,
           const float* w8, bf16* __restrict__ out)
{
  __shared__ float tile[32][33];
  const float* srcs[9] = {w0, w1, w2, w3, w4, w5, w6, w7, w8};
  const int wi = blockIdx.z;
  const float* in = srcs[wi];
  bf16* o = out + (long)wi * 65536;
  const int tx = threadIdx.x, ty = threadIdx.y;
  const int c = blockIdx.x * 32 + tx;
  const int rb = blockIdx.y * 32;
  for (int i = 0; i < 4; i++)
    tile[ty + i * 8][tx] = in[(rb + ty + i * 8) * 256 + c];
  __syncthreads();
  const int oc = rb + tx;
  const int orb = blockIdx.x * 32;
  for (int i = 0; i < 4; i++)
    o[(orb + ty + i * 8) * 256 + oc] = __float2bfloat16(tile[tx][ty + i * 8]);
}

// ---------------------------------------------------------------------------
// Elementwise / graph kernels
// ---------------------------------------------------------------------------
__global__ __launch_bounds__(256)
void cast4_k(const float* __restrict__ in, bf16* __restrict__ out)
{
  long i = ((long)blockIdx.x * 256 + threadIdx.x) * 4;
  float4 v = *(const float4*)(in + i);
  short4v o;
  o[0] = f2bits(v.x); o[1] = f2bits(v.y); o[2] = f2bits(v.z); o[3] = f2bits(v.w);
  *(short4v*)(out + i) = o;
}

// counts packed as u16 pairs in u32: cell idx -> word idx>>1, half idx&1
__global__ __launch_bounds__(256)
void edge_cnt_k(const int* __restrict__ ei, unsigned* __restrict__ cnt)
{
  int e = blockIdx.x * 256 + threadIdx.x;
  int src = ei[e], dst = ei[E_ + e];
  long idx = ((long)(src >> 8) * 256 + (dst & 255)) * 256 + (src & 255); // [g][dst][src]
  atomicAdd(&cnt[idx >> 1], 1u << ((idx & 1) * 16));
}

// deg from row-sums of cnt (+1 self loop) -> dinv. 16 lanes per row.
__global__ __launch_bounds__(256)
void deg_k(const unsigned* __restrict__ cnt, float* __restrict__ dinv)
{
  int rid = blockIdx.x * 16 + (threadIdx.x >> 4);
  int l16 = threadIdx.x & 15;
  const uint4* rp = (const uint4*)(cnt + (long)rid * 128);
  unsigned s = 0;
  for (int i = 0; i < 2; i++) {
    uint4 v = rp[l16 + i * 16];
    s += (v.x & 0xFFFF) + (v.x >> 16) + (v.y & 0xFFFF) + (v.y >> 16)
       + (v.z & 0xFFFF) + (v.z >> 16) + (v.w & 0xFFFF) + (v.w >> 16);
  }
  s += __shfl_xor(s, 1); s += __shfl_xor(s, 2);
  s += __shfl_xor(s, 4); s += __shfl_xor(s, 8);
  if (l16 == 0) dinv[rid] = rsqrtf((float)s + 1.0f);
}

// derive both bf16 adjacencies from packed counts + dinv (+ GCN self-loop)
__global__ __launch_bounds__(256)
void adj_derive_k(const unsigned* __restrict__ cnt, const float* __restrict__ dinv,
                  bf16* __restrict__ gin, bf16* __restrict__ gcn)
{
  long i = ((long)blockIdx.x * 256 + threadIdx.x) * 4;   // cell index
  uint2 cp = *(const uint2*)(cnt + (i >> 1));
  float cv[4] = {(float)(cp.x & 0xFFFF), (float)(cp.x >> 16),
                 (float)(cp.y & 0xFFFF), (float)(cp.y >> 16)};
  long row = i >> 8;            // g*256 + dst
  int g = (int)(row >> 8), dst = (int)(row & 255);
  int src0 = (int)(i & 255);
  float dd = dinv[row];
  const float* ds = dinv + (long)g * 256 + src0;
  short4v oi, oc;
  for (int j = 0; j < 4; j++) {
    float gv = cv[j] * dd * ds[j];
    if (src0 + j == dst) gv += dd * dd;
    oi[j] = f2bits(cv[j]);
    oc[j] = f2bits(gv);
  }
  *(short4v*)(gin + i) = oi;
  *(short4v*)(gcn + i) = oc;
}

// BN(e0),BN(e1) stats -> global mean/std(ddof=1) -> mix coefficients
__global__ __launch_bounds__(256)
void expert_stats_k(const float* __restrict__ S0, const float* __restrict__ SS0,
                    const float* __restrict__ S1, const float* __restrict__ SS1,
                    const float* __restrict__ gkv, const float* __restrict__ bkv,
                    float* __restrict__ kA, float* __restrict__ kB,
                    float* __restrict__ kC)
{
  const int d = threadIdx.x;
  const float invN = 1.0f / 32768.0f;
  float m0 = S0[d] * invN, v0 = SS0[d] * invN - m0 * m0;
  float a0 = gkv[d] * rsqrtf(v0 + 1e-5f), c0 = bkv[d] - m0 * a0;
  float m1 = S1[d] * invN, v1 = SS1[d] * invN - m1 * m1;
  float a1 = gkv[d] * rsqrtf(v1 + 1e-5f), c1 = bkv[d] - m1 * a1;
  float gsum = a0 * S0[d] + 32768.0f * c0 + a1 * S1[d] + 32768.0f * c1;
  float gss  = a0 * a0 * SS0[d] + 2.0f * a0 * c0 * S0[d] + 32768.0f * c0 * c0
             + a1 * a1 * SS1[d] + 2.0f * a1 * c1 * S1[d] + 32768.0f * c1 * c1;
  __shared__ float r1[256], r2[256];
  r1[d] = gsum; r2[d] = gss;
  __syncthreads();
  for (int s = 128; s > 0; s >>= 1) {
    if (d < s) { r1[d] += r1[d + s]; r2[d] += r2[d + s]; }
    __syncthreads();
  }
  const float cntall = 16777216.0f;  // 2*N*D
  float tg = r1[0], tss = r2[0];
  float gm = tg / cntall;
  float var = (tss - tg * tg / cntall) / (cntall - 1.0f);
  float gs = sqrtf(fmaxf(var, 0.f)) + 1e-8f;
  kA[d] = 0.5f * a0 / gs;
  kB[d] = 0.5f * a1 / gs;
  kC[d] = 0.5f * (c0 + c1 - 2.0f * gm) / gs;
}

__global__ __launch_bounds__(256)
void kv_mix_k(const bf16* __restrict__ hgcn, const bf16* __restrict__ hgin,
              const bf16* __restrict__ xb, const float* __restrict__ kA,
              const float* __restrict__ kB, const float* __restrict__ kC,
              bf16* __restrict__ kv)
{
  long i = ((long)blockIdx.x * 256 + threadIdx.x) * 8;
  int d0 = (int)(i & 255);
  short8 a = *(const short8*)(hgcn + i);
  short8 b = *(const short8*)(hgin + i);
  short8 c = *(const short8*)(xb + i);
  short8 o;
  for (int j = 0; j < 8; j++) {
    int d = d0 + j;
    float v = kA[d] * bits2f(a[j]) + kB[d] * bits2f(b[j]) + kC[d] + 0.1f * bits2f(c[j]);
    o[j] = f2bits(v);
  }
  *(short8*)(kv + i) = o;
}

// MODE: 1 = write f32, 2 = write bf16
template<int MODE>
__global__ __launch_bounds__(256)
void bn_apply_k(const bf16* __restrict__ in, const float* __restrict__ S,
                const float* __restrict__ SSq, const float* __restrict__ gg,
                const float* __restrict__ bb, float* __restrict__ outf,
                bf16* __restrict__ outb)
{
  long i = ((long)blockIdx.x * 256 + threadIdx.x) * 8;
  int d0 = (int)(i & 255);
  short8 v = *(const short8*)(in + i);
  const float invN = 1.0f / 32768.0f;
  float4 o0, o1; short8 o8;
  for (int j = 0; j < 8; j++) {
    int d = d0 + j;
    float m = S[d] * invN;
    float var = SSq[d] * invN - m * m;
    float a = gg[d] * rsqrtf(var + 1e-5f);
    float c = bb[d] - m * a;
    float o = a * bits2f(v[j]) + c;
    if (MODE & 1) { if (j < 4) (&o0.x)[j] = o; else (&o1.x)[j - 4] = o; }
    if (MODE & 2) o8[j] = f2bits(o);
  }
  if (MODE & 1) { *(float4*)(outf + i) = o0; *(float4*)(outf + i + 4) = o1; }
  if (MODE & 2) *(short8*)(outb + i) = o8;
}

// ---------------------------------------------------------------------------
// Workspace layout (bytes)
// ---------------------------------------------------------------------------
static constexpr size_t OFF_S0 = 0, OFF_SS0 = 1024, OFF_S1 = 2048, OFF_SS1 = 3072;
static constexpr size_t OFF_S2 = 4096, OFF_SS2 = 5120, OFF_S3 = 6144, OFF_SS3 = 7168;
static constexpr size_t OFF_KA = 8192, OFF_KB = 9216, OFF_KC = 10240;
static constexpr size_t OFF_CNT = 16384;                       // u16 counts [B][S][S]
static constexpr size_t CNT_BYTES = (size_t)B_ * S_ * S_ * 2;  // 16777216
static constexpr size_t ZERO_BYTES = OFF_CNT + CNT_BYTES;      // memset region
static constexpr size_t OFF_DINV = ZERO_BYTES;                 // 131072
static constexpr size_t OFF_W = OFF_DINV + 131072;             // bf16 weights 1703936
static constexpr size_t NDB2 = (size_t)N_ * D_ * 2;            // 16777216
static constexpr size_t OFF_ADJGINB = OFF_W + 1703936;
static constexpr size_t OFF_ADJGCNB = OFF_ADJGINB + NDB2;
static constexpr size_t OFF_XB   = OFF_ADJGCNB + NDB2;
static constexpr size_t OFF_XT   = OFF_XB + NDB2;
static constexpr size_t OFF_XWB  = OFF_XT + NDB2;
static constexpr size_t OFF_XWT  = OFF_XWB + NDB2;   // f1b spans XWT+KV (33.5MB)
static constexpr size_t OFF_KV   = OFF_XWT + NDB2;
static constexpr size_t OFF_HGCN = OFF_KV + NDB2;
static constexpr size_t OFF_HGIN = OFF_HGCN + NDB2;

extern "C" void kernel_launch(void* const* d_in, const int* in_sizes, int n_in,
                              void* d_out, int out_size, void* d_ws, size_t ws_size,
                              hipStream_t stream)
{
  (void)in_sizes; (void)n_in; (void)out_size; (void)ws_size;
  const float* x      = (const float*)d_in[0];
  const int*   ei     = (const int*)d_in[1];
  const float* W_gcn  = (const float*)d_in[2];
  const float* b_gcn  = (const float*)d_in[3];
  const float* W_gin1 = (const float*)d_in[4];
  const float* b_gin1 = (const float*)d_in[5];
  const float* W_gin2 = (const float*)d_in[6];
  const float* b_gin2 = (const float*)d_in[7];
  const float* g_kv   = (const float*)d_in[8];
  const float* be_kv  = (const float*)d_in[9];
  const float* Wq1    = (const float*)d_in[10];
  const float* bq1    = (const float*)d_in[11];
  const float* Wq2    = (const float*)d_in[12];
  const float* bq2    = (const float*)d_in[13];
  const float* Wq_a   = (const float*)d_in[14];
  const float* bq_a   = (const float*)d_in[15];
  const float* Wk_a   = (const float*)d_in[16];
  const float* bk_a   = (const float*)d_in[17];
  const float* Wv_a   = (const float*)d_in[18];
  const float* bv_a   = (const float*)d_in[19];
  const float* Wo_a   = (const float*)d_in[20];
  const float* bo_a   = (const float*)d_in[21];
  const float* g_attn = (const float*)d_in[22];
  const float* be_attn= (const float*)d_in[23];
  const float* Wf1    = (const float*)d_in[24];
  const float* bf1    = (const float*)d_in[25];
  const float* Wf2    = (const float*)d_in[26];
  const float* bf2    = (const float*)d_in[27];
  const float* g2     = (const float*)d_in[28];
  const float* be2    = (const float*)d_in[29];

  char* ws = (char*)d_ws;
  float* S0  = (float*)(ws + OFF_S0);  float* SS0 = (float*)(ws + OFF_SS0);
  float* S1  = (float*)(ws + OFF_S1);  float* SS1 = (float*)(ws + OFF_SS1);
  float* S2  = (float*)(ws + OFF_S2);  float* SS2 = (float*)(ws + OFF_SS2);
  float* S3  = (float*)(ws + OFF_S3);  float* SS3 = (float*)(ws + OFF_SS3);
  float* kA  = (float*)(ws + OFF_KA);  float* kB  = (float*)(ws + OFF_KB);
  float* kC  = (float*)(ws + OFF_KC);
  unsigned* cntA = (unsigned*)(ws + OFF_CNT);
  float* dinv = (float*)(ws + OFF_DINV);
  bf16* wT = (bf16*)(ws + OFF_W);
  bf16 *WgcnT = wT,            *Wgin1T = wT + 65536,  *Wgin2T = wT + 131072;
  bf16 *Wq1T  = wT + 196608,   *Wq2T   = wT + 262144, *WqaT   = wT + 327680;
  bf16 *WkaT  = wT + 393216,   *WvaT   = wT + 458752, *WoaT   = wT + 524288;
  bf16 *Wf1T  = wT + 589824,   *Wf2T   = wT + 720896;
  bf16* adjGINb = (bf16*)(ws + OFF_ADJGINB);
  bf16* adjGCNb = (bf16*)(ws + OFF_ADJGCNB);
  bf16* xb    = (bf16*)(ws + OFF_XB);
  bf16* xT    = (bf16*)(ws + OFF_XT);
  bf16* xw_bf = (bf16*)(ws + OFF_XWB);
  bf16* xwT   = (bf16*)(ws + OFF_XWT);
  bf16* kv_bf = (bf16*)(ws + OFF_KV);
  bf16* hgcnb = (bf16*)(ws + OFF_HGCN);
  bf16* hginb = (bf16*)(ws + OFF_HGIN);
  // lifetime-disjoint aliases
  bf16* gin_in = xw_bf;                    // after xw transposed
  bf16* gin_h  = adjGCNb;                  // after GCN-agg GEMM consumed adj
  bf16* qhb    = adjGCNb;                  // after gin2 GEMM consumed gin_h
  bf16* khb    = adjGINb;                  // after GIN-agg GEMM consumed adj
  bf16* q1b    = xT;                       // after GIN-agg GEMM consumed xT
  bf16* qb     = xw_bf;                    // after gin1 consumed gin_in
  bf16* vhb    = hgcnb;                    // after kv_mix consumed hgcn
  bf16* ob     = hginb;                    // after kv_mix consumed hgin
  bf16* tbufb  = (bf16*)(ws + OFF_CNT);    // after adj_derive consumed cnt
  bf16* hb     = xb;                       // after o-GEMM consumed xb resid
  bf16* f1b    = (bf16*)(ws + OFF_XWT);    // spans XWT+KV, after va GEMM
  bf16* t2b    = adjGCNb;                  // after attn consumed qhb
  float* outp  = (float*)d_out;

  hipMemsetAsync(d_ws, 0, ZERO_BYTES, stream);

  dim3 tb(32, 8);
  // weights -> transposed bf16 (one launch for the nine DxD, two for FFN)
  w9t_k<<<dim3(8, 8, 9), tb, 0, stream>>>(W_gcn, W_gin1, W_gin2, Wq1, Wq2,
                                          Wq_a, Wk_a, Wv_a, Wo_a, wT);
  transpose_cast_k<float><<<dim3(16, 8, 1), tb, 0, stream>>>(Wf1, Wf1T, 512, 256, 0, 0);
  transpose_cast_k<float><<<dim3(8, 16, 1), tb, 0, stream>>>(Wf2, Wf2T, 256, 512, 0, 0);
  // x casts
  cast4_k<<<8192, 256, 0, stream>>>(x, xb);
  transpose_cast_k<float><<<dim3(8, 8, 128), tb, 0, stream>>>(x, xT, 256, 256, 65536, 65536);
  // graph prep: one packed-u16 atomic per edge, then clean passes
  edge_cnt_k<<<2048, 256, 0, stream>>>(ei, cntA);
  deg_k<<<2048, 256, 0, stream>>>(cntA, dinv);
  adj_derive_k<<<8192, 256, 0, stream>>>(cntA, dinv, adjGINb, adjGCNb);
  // xw = x @ W_gcn, then per-graph transpose
  gemm_bt<16><<<dim3(256, 2, 1), 256, 0, stream>>>(xb, WgcnT, nullptr, nullptr,
      nullptr, xw_bf, nullptr, nullptr, N_, 256, 256, 0, 0, 0);
  transpose_cast_k<bf16><<<dim3(8, 8, 128), tb, 0, stream>>>(xw_bf, xwT, 256, 256, 65536, 65536);
  // h_gcn = AdjGCN @ xw + b_gcn  [stats S0] -> bf16
  gemm_bt<50><<<dim3(2, 2, 128), 256, 0, stream>>>(adjGCNb, xwT, b_gcn, nullptr,
      nullptr, hgcnb, S0, SS0, 256, 256, 256, 65536, 65536, 65536);
  // gin_in = AdjGIN @ x + x  (resid bf16 = xb) -> bf16
  gemm_bt<80><<<dim3(2, 2, 128), 256, 0, stream>>>(adjGINb, xT, nullptr, xb,
      nullptr, gin_in, nullptr, nullptr, 256, 256, 256, 65536, 65536, 65536);
  // GIN MLP
  gemm_bt<19><<<dim3(256, 2, 1), 256, 0, stream>>>(gin_in, Wgin1T, b_gin1, nullptr,
      nullptr, gin_h, nullptr, nullptr, N_, 256, 256, 0, 0, 0);
  gemm_bt<50><<<dim3(256, 2, 1), 256, 0, stream>>>(gin_h, Wgin2T, b_gin2, nullptr,
      nullptr, hginb, S1, SS1, N_, 256, 256, 0, 0, 0);
  expert_stats_k<<<1, 256, 0, stream>>>(S0, SS0, S1, SS1, g_kv, be_kv, kA, kB, kC);
  kv_mix_k<<<4096, 256, 0, stream>>>(hgcnb, hginb, xb, kA, kB, kC, kv_bf);
  // q MLP + attention projections
  gemm_bt<19><<<dim3(256, 2, 1), 256, 0, stream>>>(xb, Wq1T, bq1, nullptr,
      nullptr, q1b, nullptr, nullptr, N_, 256, 256, 0, 0, 0);
  gemm_bt<18><<<dim3(256, 2, 1), 256, 0, stream>>>(q1b, Wq2T, bq2, nullptr,
      nullptr, qb, nullptr, nullptr, N_, 256, 256, 0, 0, 0);
  gemm_bt<18><<<dim3(256, 2, 1), 256, 0, stream>>>(qb, WqaT, bq_a, nullptr,
      nullptr, qhb, nullptr, nullptr, N_, 256, 256, 0, 0, 0);
  gemm_bt<18><<<dim3(256, 2, 1), 256, 0, stream>>>(kv_bf, WkaT, bk_a, nullptr,
      nullptr, khb, nullptr, nullptr, N_, 256, 256, 0, 0, 0);
  gemm_bt<18><<<dim3(256, 2, 1), 256, 0, stream>>>(kv_bf, WvaT, bv_a, nullptr,
      nullptr, vhb, nullptr, nullptr, N_, 256, 256, 0, 0, 0);
  attn_k<<<dim3(8, 128), 256, 0, stream>>>(qhb, khb, vhb, ob);
  // t = x + o @ Wo_a + bo_a  [stats S2] -> bf16
  gemm_bt<114><<<dim3(256, 2, 1), 256, 0, stream>>>(ob, WoaT, bo_a, xb,
      nullptr, tbufb, S2, SS2, N_, 256, 256, 0, 0, 0);
  bn_apply_k<2><<<4096, 256, 0, stream>>>(tbufb, S2, SS2, g_attn, be_attn, nullptr, hb);
  // FFN
  gemm_bt<19><<<dim3(256, 4, 1), 256, 0, stream>>>(hb, Wf1T, bf1, nullptr,
      nullptr, f1b, nullptr, nullptr, N_, 512, 256, 0, 0, 0);
  gemm_bt<114><<<dim3(256, 2, 1), 256, 0, stream>>>(f1b, Wf2T, bf2, hb,
      nullptr, t2b, S3, SS3, N_, 256, 512, 0, 0, 0);
  bn_apply_k<1><<<4096, 256, 0, stream>>>(t2b, S3, SS3, g2, be2, outp, nullptr);
}